// Round 2
// baseline (395.772 us; speedup 1.0000x reference)
//
#include <hip/hip_runtime.h>
#include <stdint.h>

// Problem constants
#define ZSIZE   8388608      // 32*256*32*32
#define NPIX    32768        // 32*32*32
#define IDX_OFF ZSIZE        // idx output offset (floats) in d_out
#define LOSS_OFF (ZSIZE + NPIX)
#define ET_OFF  1024         // Et fp32 [256][1024] scratch (for kse)
#define E1_OFF  263168       // e1 bf16 [1024][256] (131072 floats)
#define ZT_OFF  394240       // zt bf16 [32][1024][256] (4194304 floats)
#define CAP     24           // candidate slots per pixel
#define WWIN    6.0e-3f      // window >= 2*eps_bound (eps<=1.7e-3, margin 1.8x)

using v8s = __attribute__((ext_vector_type(8))) short;   // 8 bf16 (4 VGPR)
using v4f = __attribute__((ext_vector_type(4))) float;   // MFMA acc

__device__ __forceinline__ unsigned short bf16rne(float f) {
  unsigned u = __float_as_uint(f);
  return (unsigned short)((u + 0x7FFFu + ((u >> 16) & 1u)) >> 16);
}

// ---------------------------------------------------------------------------
// ktr: transpose embedding E[1024][256] -> Et[256][1024] (feeds kse only)
// ---------------------------------------------------------------------------
__global__ __launch_bounds__(256) void ktr(const float* __restrict__ E,
                                           float* __restrict__ out) {
  __shared__ float tile[64][65];
  const int k0 = blockIdx.x * 64;
  const int c0 = blockIdx.y * 64;
  const int t = threadIdx.x;
  #pragma unroll
  for (int i = 0; i < 4; i++) {
    int f = t + 256 * i;
    int r = f >> 4, q = f & 15;
    float4 e = *(const float4*)(E + (k0 + r) * 256 + c0 + 4 * q);
    tile[r][4 * q + 0] = e.x; tile[r][4 * q + 1] = e.y;
    tile[r][4 * q + 2] = e.z; tile[r][4 * q + 3] = e.w;
  }
  __syncthreads();
  #pragma unroll
  for (int i = 0; i < 4; i++) {
    int f = t + 256 * i;
    int cr = f >> 4, kq = f & 15;
    float4 o;
    o.x = tile[4 * kq + 0][cr];
    o.y = tile[4 * kq + 1][cr];
    o.z = tile[4 * kq + 2][cr];
    o.w = tile[4 * kq + 3][cr];
    *(float4*)(out + ET_OFF + (c0 + cr) * 1024 + k0 + 4 * kq) = o;
  }
}

// ---------------------------------------------------------------------------
// kse: se[k] = ascending-c sequential fp32 chain of E[k][c]^2 (bit-faithful)
// ---------------------------------------------------------------------------
__global__ __launch_bounds__(256) void kse(float* __restrict__ out) {
  const int k = blockIdx.x * 256 + threadIdx.x;
  const float* Et = out + ET_OFF;
  float acc = 0.0f;
  #pragma unroll 8
  for (int c = 0; c < 256; c++) {
    float v = Et[c * 1024 + k];
    acc = __fadd_rn(acc, __fmul_rn(v, v));
  }
  out[k] = acc;
}

// ---------------------------------------------------------------------------
// ke1: e1 = bf16_rne(E), [1024][256] row-major (B-operand source)
// ---------------------------------------------------------------------------
__global__ __launch_bounds__(256) void ke1(const float* __restrict__ E,
                                           float* __restrict__ out) {
  unsigned short* e1 = (unsigned short*)(out + E1_OFF);
  int g = blockIdx.x * 256 + threadIdx.x;      // 65536 threads x 4 elems
  float4 v = *(const float4*)(E + 4 * g);
  ushort4 o;
  o.x = bf16rne(v.x); o.y = bf16rne(v.y); o.z = bf16rne(v.z); o.w = bf16rne(v.w);
  *(ushort4*)(e1 + 4 * g) = o;
}

// ---------------------------------------------------------------------------
// kzt: zt[b][n][c] = bf16_rne(zz[c][n]).  zz[c][n] = z.flat[b*262144 +
// m*1024 + 4c + w0] with n = w0*256 + m (mapping verified by the absmax=0
// baseline).  Row n holds 256 contiguous bf16 channels -> A-frag loads are
// per-lane 16B contiguous.
// ---------------------------------------------------------------------------
__global__ __launch_bounds__(256) void kzt(const float* __restrict__ z,
                                           float* __restrict__ out) {
  __shared__ float tile[16][1028];   // 16 z-rows x 1024, pad 1028 (reads 2-way)
  unsigned short* zt = (unsigned short*)(out + ZT_OFF);
  const int mg = blockIdx.x;         // 0..15 (16-row group)
  const int b  = blockIdx.y;         // 0..31
  const int t = threadIdx.x;
  #pragma unroll
  for (int i = 0; i < 16; i++) {     // row m=i, q=t: coalesced float4 loads
    float4 v = *(const float4*)(z + (size_t)b * 262144 + (size_t)(mg * 16 + i) * 1024 + 4 * t);
    *(float4*)&tile[i][4 * t] = v;
  }
  __syncthreads();
  const int m = t & 15, w0 = (t >> 4) & 3;   // R = t&63 spans (m,w0)
  const int n = w0 * 256 + mg * 16 + m;
  #pragma unroll
  for (int i = 0; i < 8; i++) {
    int g = 4 * i + (t >> 6);        // 0..31: 8-channel group
    int c0 = 8 * g;
    unsigned short o[8];
    #pragma unroll
    for (int j = 0; j < 8; j++)
      o[j] = bf16rne(tile[m][4 * (c0 + j) + w0]);
    *(uint4*)(zt + ((size_t)(b * 1024 + n)) * 256 + c0) = *(const uint4*)o;
  }
}

// ---------------------------------------------------------------------------
// kmain: MFMA approximate distances + provably-sound exact rescreen.
// Block = (ccg,b): 64 px (16 z-rows x 4 w0) x 1024 codes.
// Per wave: 4 resident A px-tiles (z bf16, 128 VGPR), streams 16 code-tiles
// (tile = ti*4+w) as B-frags direct from e1 (1 dwordx4 per 4 MFMA).
// d_approx = (se+sz) - 2*mfma_dot; |d_approx - d_exact| <= 1.7e-3 rigorous.
// Candidates {d_approx <= running_min + W}, W=6e-3 >= 2*eps: contains every
// exact winner incl. ties.  Exact rescreen = bit-identical fp32 chain
// (ascending c, __fmaf_rn) from VsT (exact z copy) and original E.
// Candidate overflow (P~1e-5/px) -> wave-cooperative exact full scan.
// MFMA C/D: col=lane&15 (code), row=(lane>>4)*4+reg (px-row) [m89-verified].
// A/B packed with identical (lane-half,elem)->c convention so any internal
// k-permutation cancels in the sum.
// ---------------------------------------------------------------------------
__global__ __launch_bounds__(256, 2) void kmain(const float* __restrict__ z,
                                                const float* __restrict__ E,
                                                float* __restrict__ out) {
  __shared__ __attribute__((aligned(16))) float VsT[256][65];  // exact z, [c][p], pad 65
  __shared__ __attribute__((aligned(16))) float szs[64];
  __shared__ __attribute__((aligned(16))) float dmins[64];
  __shared__ int   candK[64 * CAP];
  __shared__ float candD[64 * CAP];
  __shared__ int   cnt[64];

  const int t = threadIdx.x;
  const int ccg = blockIdx.x, b = blockIdx.y;
  const int cc0 = ccg * 16;
  const int lane = t & 63, w = t >> 6;
  const int r = t & 15, h = (t >> 4) & 3;
  const float* zb = z + (size_t)b * 262144;
  const float* se_g = out;
  const unsigned short* e1 = (const unsigned short*)(out + E1_OFF);
  const unsigned short* zt = (const unsigned short*)(out + ZT_OFF);

  if (t < 64) { cnt[t] = 0; dmins[t] = 3.4e38f; }

  // ---- stage VsT[c][p] = z[row cc0+i][4c+w0], p = 4i+w0 (free transpose:
  // each float4 is 4 consecutive w0 of one channel -> contiguous b128 write,
  // 2-way banks) ----
  #pragma unroll
  for (int i = 0; i < 16; i++) {
    float4 v = *(const float4*)(zb + (cc0 + i) * 1024 + 4 * t);
    *(float4*)&VsT[t][4 * i] = v;
  }
  __syncthreads();

  // ---- sz: exact ascending-c chain per px (wave 0; conflict-free columns) ----
  if (t < 64) {
    float a = 0.0f;
    #pragma unroll 8
    for (int c = 0; c < 256; c++)
      a = __fadd_rn(a, __fmul_rn(VsT[c][t], VsT[c][t]));
    szs[t] = a;
  }

  // ---- A-frags: 32 contiguous 16B loads from zt (waves 1-3 overlap sz) ----
  v8s A_[4][8];
  #pragma unroll
  for (int T = 0; T < 4; T++) {
    const unsigned short* base =
        zt + ((size_t)(b * 1024 + T * 256 + cc0 + r)) * 256 + 8 * h;
    #pragma unroll
    for (int s = 0; s < 8; s++)
      A_[T][s] = *(const v8s*)(base + 32 * s);
  }
  __syncthreads();

  float szr_[16];
  #pragma unroll
  for (int reg = 0; reg < 4; reg++) {
    float4 s4 = *(const float4*)&szs[16 * h + 4 * reg];
    szr_[4 * reg + 0] = s4.x; szr_[4 * reg + 1] = s4.y;
    szr_[4 * reg + 2] = s4.z; szr_[4 * reg + 3] = s4.w;
  }

  float bestd_[16], d0_[16];
  #pragma unroll
  for (int j = 0; j < 16; j++) { bestd_[j] = 3.4e38f; d0_[j] = 3.4e38f; }

  volatile float* dminv = dmins;   // stale reads are sound (threshold >= final min)

  for (int ti = 0; ti < 16; ti++) {
    const int code0 = ti * 64 + w * 16;
    const unsigned short* bb = e1 + (size_t)(code0 + r) * 256 + 8 * h;
    v4f acc[4];
    #pragma unroll
    for (int T = 0; T < 4; T++) acc[T] = (v4f){0.f, 0.f, 0.f, 0.f};
    #pragma unroll
    for (int s = 0; s < 8; s++) {
      v8s B_ = *(const v8s*)(bb + 32 * s);
      #pragma unroll
      for (int T = 0; T < 4; T++)
        acc[T] = __builtin_amdgcn_mfma_f32_16x16x32_bf16(A_[T][s], B_, acc[T], 0, 0, 0);
    }
    const int kl = code0 + r;          // this lane's D-column code
    const float se_l = se_g[kl];
    #pragma unroll
    for (int T = 0; T < 4; T++) {
      #pragma unroll
      for (int reg = 0; reg < 4; reg++) {
        const int j = 4 * reg + T;
        const int p = 16 * h + 4 * reg + T;   // px = row m*4 + w0, m = 4h+reg
        float dd = (se_l + szr_[j]) - 2.0f * acc[T][reg];
        float thr = fminf(bestd_[j], dminv[p]);
        if (ti == 0) {
          d0_[j] = dd;                 // peel: no threshold yet; retro-append
        } else if (dd <= thr + WWIN) {
          int o = atomicAdd(&cnt[p], 1);
          if (o < CAP) { candK[p * CAP + o] = kl; candD[p * CAP + o] = dd; }
        }
        if (dd < bestd_[j]) {
          bestd_[j] = dd;
          atomicMin((int*)&dmins[p], __float_as_int(dd));  // positive floats: int-order ok
        }
      }
    }
  }

  // ---- retro-append tile 0 against (near-)final min ----
  #pragma unroll
  for (int T = 0; T < 4; T++) {
    #pragma unroll
    for (int reg = 0; reg < 4; reg++) {
      const int j = 4 * reg + T;
      const int p = 16 * h + 4 * reg + T;
      float dd = d0_[j];
      if (dd <= dminv[p] + WWIN) {
        int o = atomicAdd(&cnt[p], 1);
        if (o < CAP) { candK[p * CAP + o] = w * 16 + r; candD[p * CAP + o] = dd; }
      }
    }
  }
  __syncthreads();   // all appends + final dmins visible

  // ---- exact rescreen: bit-identical fp32 chain for surviving candidates ----
  for (int i = t; i < 64 * CAP; i += 256) {
    int p = i / CAP, slot = i - p * CAP;
    int cn = cnt[p];
    if (cn > CAP || slot >= cn) continue;     // overflow px -> fallback
    float dd = candD[i];
    if (dd > dmins[p] + WWIN) { candD[i] = 3.4e38f; continue; }
    int k = candK[i];
    const float* er = E + (size_t)k * 256;
    float dot = 0.0f;
    #pragma unroll 8
    for (int c = 0; c < 256; c++)
      dot = __fmaf_rn(VsT[c][p], er[c], dot);
    candD[i] = __fsub_rn(__fadd_rn(se_g[k], szs[p]), __fmul_rn(2.0f, dot));
  }
  __syncthreads();

  // ---- winners: lexicographic (d,k) min == first-index argmin ----
  if (t < 64) {
    int p = t, cn = cnt[p];
    if (cn <= CAP) {
      float bd = 3.4e38f; int bi = 0x7FFFFFFF;
      for (int s2 = 0; s2 < cn; s2++) {
        float d2 = candD[p * CAP + s2]; int k2 = candK[p * CAP + s2];
        if (d2 < bd || (d2 == bd && k2 < bi)) { bd = d2; bi = k2; }
      }
      int rr = p >> 2, w0 = p & 3;
      out[IDX_OFF + b * 1024 + (w0 * 256 + cc0 + rr)] = (float)bi;
    }
  }

  // ---- fallback: overflowed px -> exact full scan by one wave (rare) ----
  for (int p = 0; p < 64; p++) {
    if (cnt[p] > CAP && (p & 3) == w) {
      float bd = 3.4e38f; int bi = 0x7FFFFFFF;
      for (int k = lane; k < 1024; k += 64) {
        const float* er = E + (size_t)k * 256;
        float dot = 0.0f;
        #pragma unroll 8
        for (int c = 0; c < 256; c++)
          dot = __fmaf_rn(VsT[c][p], er[c], dot);
        float d2 = __fsub_rn(__fadd_rn(se_g[k], szs[p]), __fmul_rn(2.0f, dot));
        if (d2 < bd || (d2 == bd && k < bi)) { bd = d2; bi = k; }
      }
      #pragma unroll
      for (int mm = 32; mm >= 1; mm >>= 1) {
        float d2 = __shfl_xor(bd, mm, 64);
        int i2 = __shfl_xor(bi, mm, 64);
        if (d2 < bd || (d2 == bd && i2 < bi)) { bd = d2; bi = i2; }
      }
      if (lane == 0) {
        int rr = p >> 2, w0 = p & 3;
        out[IDX_OFF + b * 1024 + (w0 * 256 + cc0 + rr)] = (float)bi;
      }
    }
  }
}

// ---------------------------------------------------------------------------
// kout: z_q_st = fl(zp + fl(zq - zp)); per-block loss partial -> d_ws
// ---------------------------------------------------------------------------
__global__ __launch_bounds__(256) void kout(const float* __restrict__ z,
                                            const float* __restrict__ E,
                                            float* __restrict__ out,
                                            float* __restrict__ ws) {
  __shared__ float red[4];
  const int t = threadIdx.x;
  const size_t g4 = (size_t)blockIdx.x * 256 + t;
  const size_t g = g4 * 4;
  const int b = (int)(g >> 18);
  const int c = (int)((g >> 10) & 255);
  const int n = (int)(g & 1023);

  float4 zp = *(const float4*)(z + g);
  float4 idxf = *(const float4*)(out + IDX_OFF + b * 1024 + n);
  int i0 = (int)idxf.x, i1 = (int)idxf.y, i2 = (int)idxf.z, i3 = (int)idxf.w;
  float q0 = E[i0 * 256 + c];
  float q1 = E[i1 * 256 + c];
  float q2 = E[i2 * 256 + c];
  float q3 = E[i3 * 256 + c];
  float d0 = __fsub_rn(q0, zp.x);
  float d1 = __fsub_rn(q1, zp.y);
  float d2 = __fsub_rn(q2, zp.z);
  float d3 = __fsub_rn(q3, zp.w);
  float4 o;
  o.x = __fadd_rn(zp.x, d0);
  o.y = __fadd_rn(zp.y, d1);
  o.z = __fadd_rn(zp.z, d2);
  o.w = __fadd_rn(zp.w, d3);
  *(float4*)(out + g) = o;

  float s = d0 * d0 + d1 * d1 + d2 * d2 + d3 * d3;
  #pragma unroll
  for (int off = 32; off > 0; off >>= 1) s += __shfl_down(s, off);
  if ((t & 63) == 0) red[t >> 6] = s;
  __syncthreads();
  if (t == 0) ws[blockIdx.x] = red[0] + red[1] + red[2] + red[3];
}

// ---------------------------------------------------------------------------
// kfin: loss = 1.25 * (sum(ws)/N)
// ---------------------------------------------------------------------------
__global__ __launch_bounds__(256) void kfin(const float* __restrict__ ws,
                                            float* __restrict__ out) {
  __shared__ float red[4];
  const int t = threadIdx.x;
  float s = 0.0f;
  #pragma unroll
  for (int i = 0; i < 32; i++) s += ws[t + 256 * i];
  #pragma unroll
  for (int off = 32; off > 0; off >>= 1) s += __shfl_down(s, off);
  if ((t & 63) == 0) red[t >> 6] = s;
  __syncthreads();
  if (t == 0) {
    float S = red[0] + red[1] + red[2] + red[3];
    float m = S / 8388608.0f;
    out[LOSS_OFF] = __fadd_rn(m, __fmul_rn(0.25f, m));
  }
}

extern "C" void kernel_launch(void* const* d_in, const int* in_sizes, int n_in,
                              void* d_out, int out_size, void* d_ws, size_t ws_size,
                              hipStream_t stream) {
  const float* z = (const float*)d_in[0];    // [32,256,32,32]
  const float* E = (const float*)d_in[1];    // [1024,256]
  float* out = (float*)d_out;
  float* ws = (float*)d_ws;

  ktr<<<dim3(16, 4), 256, 0, stream>>>(E, out);
  kse<<<dim3(4), 256, 0, stream>>>(out);
  ke1<<<dim3(256), 256, 0, stream>>>(E, out);
  kzt<<<dim3(16, 32), 256, 0, stream>>>(z, out);
  kmain<<<dim3(16, 32), 256, 0, stream>>>(z, E, out);
  kout<<<dim3(8192), 256, 0, stream>>>(z, E, out, ws);
  kfin<<<dim3(1), 256, 0, stream>>>(ws, out);
}